// Round 2
// baseline (153.641 us; speedup 1.0000x reference)
//
#include <hip/hip_runtime.h>
#include <hip/hip_bf16.h>

#define BB 4
#define TT 256
#define LL 128
#define EE 64
#define SCALE 0.125f  // 1/sqrt(64)

// Kernel A: one block per (b,l). Computes dot[t] = <note[b,t,:], harm[b,l,:]>,
// the global max M_bl of raw = dot*SCALE, then fp64 inclusive prefix sums of
// ex = exp(raw - M_bl) and ex*dot (Hillis-Steele in LDS).
// Stores P[b][t][l] = double2(Sd, Sn)  -- layout chosen so kernel B's loads
// are coalesced along l.
__global__ __launch_bounds__(256) void k_prefix(const float* __restrict__ note,
                                                const float* __restrict__ harm,
                                                double2* __restrict__ P) {
    int b = blockIdx.x >> 7;     // L=128 blocks per b
    int l = blockIdx.x & 127;
    int t = threadIdx.x;         // 256 threads = t

    __shared__ __align__(16) float h[EE];
    if (t < EE) h[t] = harm[(b * LL + l) * EE + t];
    __syncthreads();

    const float4* n4 = (const float4*)(note + (b * TT + t) * EE);
    const float4* h4 = (const float4*)h;
    float acc = 0.f;
#pragma unroll
    for (int i = 0; i < EE / 4; ++i) {
        float4 nv = n4[i];
        float4 hv = h4[i];
        acc += nv.x * hv.x + nv.y * hv.y + nv.z * hv.z + nv.w * hv.w;
    }
    float dot = acc;
    float raw = dot * SCALE;

    // block max-reduce over t
    __shared__ float red[256];
    red[t] = raw;
    __syncthreads();
#pragma unroll
    for (int off = 128; off > 0; off >>= 1) {
        if (t < off) red[t] = fmaxf(red[t], red[t + off]);
        __syncthreads();
    }
    float M = red[0];
    __syncthreads();

    float ex = __expf(raw - M);
    double vd = (double)ex;
    double vn = (double)ex * (double)dot;

    // Hillis-Steele inclusive prefix scan (fp64) over 256 elements
    __shared__ double sd[TT], sn[TT];
    sd[t] = vd;
    sn[t] = vn;
    __syncthreads();
#pragma unroll
    for (int off = 1; off < TT; off <<= 1) {
        double pd = 0.0, pn = 0.0;
        if (t >= off) { pd = sd[t - off]; pn = sn[t - off]; }
        __syncthreads();
        vd += pd;
        vn += pn;
        sd[t] = vd;
        sn[t] = vn;
        __syncthreads();
    }

    P[(b * TT + t) * LL + l] = make_double2(vd, vn);
}

// Kernel B: fully parallel output. Block = (b, s, e-tile of 8); 256 threads =
// (eo in {0,1}) x (l in [0,128)); each thread writes 4 consecutive e.
// out[b][s][e][l] = (Sn(e)-Sn(s-1)) / (Sd(e)-Sd(s-1)) for e>=s, else 0.
__global__ __launch_bounds__(256) void k_out(const double2* __restrict__ P,
                                             float* __restrict__ out) {
    int blk = blockIdx.x;
    int et = blk & 31;            // 32 e-tiles of 8
    int s  = (blk >> 5) & 255;    // T=256
    int b  = blk >> 13;
    int l  = threadIdx.x & 127;
    int eo = threadIdx.x >> 7;

    double2 Ps = make_double2(0.0, 0.0);
    if (s > 0) Ps = P[(b * TT + (s - 1)) * LL + l];

    int e0 = et * 8 + eo * 4;
    float* op = out + (size_t)(((b * TT + s) * TT) + e0) * LL + l;
    const double2* pp = P + (b * TT + e0) * LL + l;

#pragma unroll
    for (int k = 0; k < 4; ++k) {
        int e = e0 + k;
        float r = 0.f;
        if (e >= s) {                       // wave-uniform branch (e,s uniform)
            double2 Pe = pp[k * LL];
            float den = (float)(Pe.x - Ps.x);
            float num = (float)(Pe.y - Ps.y);
            r = __fdividef(num, fmaxf(den, 1e-30f));
        }
        op[k * LL] = r;
    }
}

extern "C" void kernel_launch(void* const* d_in, const int* in_sizes, int n_in,
                              void* d_out, int out_size, void* d_ws, size_t ws_size,
                              hipStream_t stream) {
    const float* note = (const float*)d_in[0];   // [B,T,E]
    const float* harm = (const float*)d_in[1];   // [B,L,E]
    float* out = (float*)d_out;                  // [B,T,T,L]

    double2* P = (double2*)d_ws;                 // [B,T,L] double2 = 2 MB

    k_prefix<<<BB * LL, 256, 0, stream>>>(note, harm, P);
    k_out<<<BB * TT * 32, 256, 0, stream>>>(P, out);
}

// Round 3
// 152.135 us; speedup vs baseline: 1.0099x; 1.0099x over previous
//
#include <hip/hip_runtime.h>
#include <hip/hip_bf16.h>

#define BB 4
#define TT 256
#define LL 128
#define EE 64
#define SCALE 0.125f  // 1/sqrt(64)

// Kernel A: one block per (b,l). dot[t] = <note[b,t,:], harm[b,l,:]>, global max
// M_bl of raw = dot*SCALE, then fp64 inclusive prefix sums of ex = exp(raw-M)
// and ex*dot. Wave-level shfl scan (6 rounds, no barrier) + one LDS round for
// inter-wave offsets. P[b][t][l] = double2(Sd, Sn) — layout makes kernel B's
// loads coalesced along l (lanes = l).
__global__ __launch_bounds__(256) void k_prefix(const float* __restrict__ note,
                                                const float* __restrict__ harm,
                                                double2* __restrict__ P) {
    int b = blockIdx.x >> 7;     // L=128 blocks per b
    int l = blockIdx.x & 127;
    int t = threadIdx.x;         // 256 threads = t
    int lane = t & 63;
    int wave = t >> 6;

    __shared__ __align__(16) float h[EE];
    if (t < EE) h[t] = harm[(b * LL + l) * EE + t];
    __syncthreads();

    const float4* n4 = (const float4*)(note + (b * TT + t) * EE);
    const float4* h4 = (const float4*)h;
    float acc = 0.f;
#pragma unroll
    for (int i = 0; i < EE / 4; ++i) {
        float4 nv = n4[i];
        float4 hv = h4[i];
        acc += nv.x * hv.x + nv.y * hv.y + nv.z * hv.z + nv.w * hv.w;
    }
    float dot = acc;
    float raw = dot * SCALE;

    // block max-reduce: wave shfl_xor then 4 wave maxes via LDS
    float m = raw;
#pragma unroll
    for (int off = 32; off > 0; off >>= 1) m = fmaxf(m, __shfl_xor(m, off));
    __shared__ float wmax[4];
    if (lane == 0) wmax[wave] = m;
    __syncthreads();
    float M = fmaxf(fmaxf(wmax[0], wmax[1]), fmaxf(wmax[2], wmax[3]));

    float ex = __expf(raw - M);
    double vd = (double)ex;
    double vn = (double)ex * (double)dot;

    // intra-wave inclusive scan (fp64) via shfl_up
#pragma unroll
    for (int off = 1; off < 64; off <<= 1) {
        double od = __shfl_up(vd, off);
        double on = __shfl_up(vn, off);
        if (lane >= off) { vd += od; vn += on; }
    }
    // inter-wave offsets
    __shared__ double wtd[4], wtn[4];
    if (lane == 63) { wtd[wave] = vd; wtn[wave] = vn; }
    __syncthreads();
    double od = 0.0, on = 0.0;
#pragma unroll
    for (int w = 0; w < 3; ++w) {
        if (w < wave) { od += wtd[w]; on += wtn[w]; }
    }
    vd += od;
    vn += on;

    P[(b * TT + t) * LL + l] = make_double2(vd, vn);
}

// Kernel B: block = (b, s-tile of 4, e-quarter of 64); 256 threads = 2 eo x 128 l.
// Each thread holds Ps for the 4 s in registers and streams 32 e's, so every Pe
// load is amortized over 4 outputs. out[b][s][e][l] =
//   (Sn(e)-Sn(s-1)) / (Sd(e)-Sd(s-1)) for e>=s, else 0.
__global__ __launch_bounds__(256) void k_out(const double2* __restrict__ P,
                                             float* __restrict__ out) {
    int blk = blockIdx.x;
    int eq = blk & 3;             // e-quarter
    int st = (blk >> 2) & 63;     // s-tile
    int b  = blk >> 8;
    int l  = threadIdx.x & 127;
    int eo = threadIdx.x >> 7;
    int s0 = st * 4;
    int e_begin = eq * 64 + eo * 32;

    double2 Ps[4];
#pragma unroll
    for (int k = 0; k < 4; ++k) {
        int s = s0 + k;
        Ps[k] = (s > 0) ? P[(b * TT + s - 1) * LL + l] : make_double2(0.0, 0.0);
    }

    const double2* pp = P + (b * TT + e_begin) * LL + l;
    float* op = out + ((size_t)(b * TT + s0) * TT + e_begin) * LL + l;
    const int srow = TT * LL;     // stride between s rows (32768 floats)

#pragma unroll 4
    for (int ke = 0; ke < 32; ++ke) {
        int e = e_begin + ke;
        if (e < s0) {             // wave-uniform: whole tile below diagonal
#pragma unroll
            for (int k = 0; k < 4; ++k) op[k * srow + ke * LL] = 0.f;
        } else {
            double2 Pe = pp[ke * LL];
#pragma unroll
            for (int k = 0; k < 4; ++k) {
                float r = 0.f;
                if (e >= s0 + k) {
                    float den = (float)(Pe.x - Ps[k].x);
                    float num = (float)(Pe.y - Ps[k].y);
                    r = __fdividef(num, fmaxf(den, 1e-30f));
                }
                op[k * srow + ke * LL] = r;
            }
        }
    }
}

extern "C" void kernel_launch(void* const* d_in, const int* in_sizes, int n_in,
                              void* d_out, int out_size, void* d_ws, size_t ws_size,
                              hipStream_t stream) {
    const float* note = (const float*)d_in[0];   // [B,T,E]
    const float* harm = (const float*)d_in[1];   // [B,L,E]
    float* out = (float*)d_out;                  // [B,T,T,L]

    double2* P = (double2*)d_ws;                 // [B,T,L] double2 = 2 MB

    k_prefix<<<BB * LL, 256, 0, stream>>>(note, harm, P);
    k_out<<<BB * 64 * 4, 256, 0, stream>>>(P, out);
}

// Round 4
// 149.787 us; speedup vs baseline: 1.0257x; 1.0157x over previous
//
#include <hip/hip_runtime.h>
#include <hip/hip_bf16.h>

#define BB 4
#define TT 256
#define LL 128
#define EE 64
#define SCALE 0.125f  // 1/sqrt(64)

// Kernel A: one block per (b,l). dot[t] = <note[b,t,:], harm[b,l,:]>, global max
// M_bl of raw = dot*SCALE, then fp64 inclusive prefix sums of ex = exp(raw-M)
// and ex*dot. Wave shfl scan + one LDS round for inter-wave offsets.
// P[b][t][l] = double2(Sd, Sn).
__global__ __launch_bounds__(256) void k_prefix(const float* __restrict__ note,
                                                const float* __restrict__ harm,
                                                double2* __restrict__ P) {
    int b = blockIdx.x >> 7;     // L=128 blocks per b
    int l = blockIdx.x & 127;
    int t = threadIdx.x;         // 256 threads = t
    int lane = t & 63;
    int wave = t >> 6;

    __shared__ __align__(16) float h[EE];
    if (t < EE) h[t] = harm[(b * LL + l) * EE + t];
    __syncthreads();

    const float4* n4 = (const float4*)(note + (b * TT + t) * EE);
    const float4* h4 = (const float4*)h;
    float acc = 0.f;
#pragma unroll
    for (int i = 0; i < EE / 4; ++i) {
        float4 nv = n4[i];
        float4 hv = h4[i];
        acc += nv.x * hv.x + nv.y * hv.y + nv.z * hv.z + nv.w * hv.w;
    }
    float dot = acc;
    float raw = dot * SCALE;

    // block max-reduce
    float m = raw;
#pragma unroll
    for (int off = 32; off > 0; off >>= 1) m = fmaxf(m, __shfl_xor(m, off));
    __shared__ float wmax[4];
    if (lane == 0) wmax[wave] = m;
    __syncthreads();
    float M = fmaxf(fmaxf(wmax[0], wmax[1]), fmaxf(wmax[2], wmax[3]));

    float ex = __expf(raw - M);
    double vd = (double)ex;
    double vn = (double)ex * (double)dot;

    // intra-wave inclusive scan (fp64) via shfl_up
#pragma unroll
    for (int off = 1; off < 64; off <<= 1) {
        double od = __shfl_up(vd, off);
        double on = __shfl_up(vn, off);
        if (lane >= off) { vd += od; vn += on; }
    }
    __shared__ double wtd[4], wtn[4];
    if (lane == 63) { wtd[wave] = vd; wtn[wave] = vn; }
    __syncthreads();
    double od = 0.0, on = 0.0;
#pragma unroll
    for (int w = 0; w < 3; ++w) {
        if (w < wave) { od += wtd[w]; on += wtn[w]; }
    }
    vd += od;
    vn += on;

    P[(b * TT + t) * LL + l] = make_double2(vd, vn);
}

// Kernel B: block covers (b, s-tile of 4, e-range of 64). 256 threads =
// (eo in [0,8)) x (lq in [0,32)); thread owns l-quad l0=lq*4 and writes
// float4 stores (4 outputs per store). Ps for the 4x4 (s x l) tile in
// registers; each Pe (4 double2) reused across the 4 s values.
__global__ __launch_bounds__(256) void k_out(const double2* __restrict__ P,
                                             float* __restrict__ out) {
    int blk = blockIdx.x;
    int eq = blk & 3;             // e-quarter: e_base = eq*64
    int st = (blk >> 2) & 63;     // s-tile:    s0 = st*4
    int b  = blk >> 8;
    int lq = threadIdx.x & 31;
    int eo = threadIdx.x >> 5;    // [0,8)
    int s0 = st * 4;
    int l0 = lq * 4;
    int e_base = eq * 64;

    // Ps[k][j] = P[b][s0+k-1][l0+j] (0 if s==0)
    double Psx[4][4], Psy[4][4];
#pragma unroll
    for (int k = 0; k < 4; ++k) {
        int s = s0 + k;
        if (s > 0) {
            const double2* ps = P + (b * TT + s - 1) * LL + l0;
#pragma unroll
            for (int j = 0; j < 4; ++j) {
                double2 v = ps[j];
                Psx[k][j] = v.x;
                Psy[k][j] = v.y;
            }
        } else {
#pragma unroll
            for (int j = 0; j < 4; ++j) { Psx[k][j] = 0.0; Psy[k][j] = 0.0; }
        }
    }

    const double2* pbase = P + b * TT * LL + l0;
    float* obase = out + ((size_t)(b * TT + s0) * TT) * LL + l0;
    const int srow = TT * LL;     // floats between s rows

#pragma unroll 2
    for (int it = 0; it < 8; ++it) {
        int e = e_base + it * 8 + eo;
        const double2* pe = pbase + e * LL;
        double2 Pe[4];
#pragma unroll
        for (int j = 0; j < 4; ++j) Pe[j] = pe[j];

#pragma unroll
        for (int k = 0; k < 4; ++k) {
            float4 r;
            float* rp = (float*)&r;
#pragma unroll
            for (int j = 0; j < 4; ++j) {
                float v = 0.f;
                if (e >= s0 + k) {
                    float den = (float)(Pe[j].x - Psx[k][j]);
                    float num = (float)(Pe[j].y - Psy[k][j]);
                    v = __fdividef(num, fmaxf(den, 1e-30f));
                }
                rp[j] = v;
            }
            *(float4*)(obase + k * srow + e * LL) = r;
        }
    }
}

extern "C" void kernel_launch(void* const* d_in, const int* in_sizes, int n_in,
                              void* d_out, int out_size, void* d_ws, size_t ws_size,
                              hipStream_t stream) {
    const float* note = (const float*)d_in[0];   // [B,T,E]
    const float* harm = (const float*)d_in[1];   // [B,L,E]
    float* out = (float*)d_out;                  // [B,T,T,L]

    double2* P = (double2*)d_ws;                 // [B,T,L] double2 = 2 MB

    k_prefix<<<BB * LL, 256, 0, stream>>>(note, harm, P);
    k_out<<<BB * 64 * 4, 256, 0, stream>>>(P, out);
}